// Round 7
// baseline (791.361 us; speedup 1.0000x reference)
//
#include <hip/hip_runtime.h>
#include <math.h>

typedef unsigned short u16;
typedef __attribute__((ext_vector_type(8))) short short8;
typedef __attribute__((ext_vector_type(4))) float f32x4;

#define Bb 256
#define Rr 6
#define Ksp 49
#define Cc 512
#define Hh 1024
#define Ee 300
#define NN (Bb*Rr)        // 1536
#define NLl 2001

__device__ __forceinline__ u16 f2b(float x) {
    union { float f; unsigned u; } c; c.f = x;
    unsigned r = c.u + 0x7fffu + ((c.u >> 16) & 1u);   // RNE, finite inputs
    return (u16)(r >> 16);
}
__device__ __forceinline__ float b2f(u16 b) {
    union { unsigned u; float f; } c; c.u = ((unsigned)b) << 16; return c.f;
}

// async global->LDS, 16B per lane; LDS dest = wave-uniform base + lane*16
#define ASYNC16(gp, lp) __builtin_amdgcn_global_load_lds( \
    (const __attribute__((address_space(1))) unsigned int*)(gp), \
    (__attribute__((address_space(3))) unsigned int*)(lp), 16, 0, 0)

// ---- weight-pool element offsets (bf16 B^T buffers, contiguous) ----
constexpr size_t O_QC   = 0;                            // [1024][640]
constexpr size_t O_AV   = O_QC   + (size_t)1024*640;    // [1024][512]
constexpr size_t O_AQQN = O_AV   + (size_t)1024*512;    // [2048][1024]
constexpr size_t O_VN   = O_AQQN + (size_t)2048*1024;   // [1024][512]
constexpr size_t O_QKV  = O_VN   + (size_t)1024*512;    // [3072][1024]
constexpr size_t O_WO   = O_QKV  + (size_t)3072*1024;   // [1024][1024]
constexpr size_t O_UQC  = O_WO   + (size_t)1024*1024;   // [1024][1664]
constexpr size_t O_CLS  = O_UQC  + (size_t)1024*1664;   // [2048][1024]
constexpr size_t WT_ELEMS = O_CLS + (size_t)2048*1024;

// ---------------- barrier-free wave-GEMM (small/medium shapes) ------------
// Each wave owns a 16x64 C-tile; A/B fragments load DIRECTLY from global to
// registers (no LDS, no __syncthreads). Compiler emits fine-grained vmcnt
// (no barrier => no vmcnt(0) drain) -> ~20 loads in flight per wave; this is
// the no-barrier analog of AITER's interleaved K-loop (R6 theory: small
// shapes are latency-bound on the barrier drain, not BW).
// Block = 4 waves stacked on M (64 rows), all sharing the SAME B addresses
// -> L1 broadcast. grid.x = N/64, grid.y = M/64. K % 128 == 0.
// A bf16 [..][lda], Bt bf16 [N][K]; epilogue identical to gemm_bf16.
__global__ void __launch_bounds__(256) wgemm_bf16(
    const u16* __restrict__ A, int lda, const u16* __restrict__ Bt,
    const float* __restrict__ bias,
    u16* __restrict__ Cb, int ldcb, float* __restrict__ Cf, int ldcf,
    int K, int split, int Nreal, int act)
{
    const int tid = threadIdx.x, wave = tid >> 6, lane = tid & 63;
    const int m0 = lane & 15, q0 = lane >> 4;

    // XCD-contiguous n-fastest tile remap (xcd = hw_lid % 8 heuristic)
    const int gn = gridDim.x;
    const int nblk = gn * gridDim.y;
    const int lid = blockIdx.y * gn + blockIdx.x;
    const int per = nblk >> 3, rem = nblk & 7;
    const int xcd = lid & 7, slot = lid >> 3;
    const int t = xcd * per + ((xcd < rem) ? xcd : rem) + slot;
    const int tm = t / gn, tn = t - tm * gn;

    const int bm = tm * 64 + wave * 16;
    const int bn = tn * 64;

    const u16* arow = A + (size_t)(bm + m0) * lda + q0 * 8;
    const u16* brow0 = Bt + (size_t)(bn + m0) * K + q0 * 8;   // j strides by 16*K

    f32x4 acc[4];
    #pragma unroll
    for (int j = 0; j < 4; j++) acc[j] = (f32x4){0.f, 0.f, 0.f, 0.f};

    for (int kt = 0; kt < K; kt += 128) {
        #pragma unroll
        for (int u = 0; u < 4; u++) {
            const int k = kt + u * 32;
            const short8 av = *(const short8*)(arow + k);
            #pragma unroll
            for (int j = 0; j < 4; j++) {
                const short8 bv = *(const short8*)(brow0 + (size_t)j * 16 * K + k);
                acc[j] = __builtin_amdgcn_mfma_f32_16x16x32_bf16(av, bv, acc[j], 0, 0, 0);
            }
        }
    }

    #pragma unroll
    for (int j = 0; j < 4; j++) {
        const int col = bn + j * 16 + m0;
        if (col >= Nreal) continue;
        const float bv = bias ? bias[col] : 0.f;
        #pragma unroll
        for (int r = 0; r < 4; r++) {
            const int row = bm + q0 * 4 + r;    // C/D: col=lane&15, row=q0*4+r
            float v = acc[j][r] + bv;
            if (act) v = fmaxf(v, 0.f);
            if (col < split) Cb[(size_t)row * ldcb + col] = f2b(v);
            else             Cf[(size_t)row * ldcf + col - split] = v;
        }
    }
}

// ---------------- bf16 MFMA GEMM, LDS dbuf (big M=25088 GEMM only) --------
template<int BM, int BN, int BK>
__global__ void __launch_bounds__(256) gemm_bf16(
    const u16* __restrict__ A, int lda, const u16* __restrict__ Bt,
    const float* __restrict__ bias,
    u16* __restrict__ Cb, int ldcb, float* __restrict__ Cf, int ldcf,
    int K, int split, int Nreal, int act)
{
    constexpr int SM = BM / 16, SN = BN / 16;    // 16-row sub-tiles
    constexpr int KG = BK / 32;                  // k-granules per iteration
    constexpr int WM = BM / 32, WN = BN / 32;    // per-wave 16x16 tiles
    constexpr int BUF = (SM + SN) * KG * 512;    // u16 per buffer
    __shared__ u16 lds[2 * BUF];
    const int tid  = threadIdx.x;
    const int wave = tid >> 6, lane = tid & 63;
    const int m0 = lane & 15, q0 = lane >> 4;

    const int gn = gridDim.x;
    const int nblk = gn * gridDim.y;
    const int lid = blockIdx.y * gn + blockIdx.x;
    const int per = nblk >> 3, rem = nblk & 7;
    const int xcd = lid & 7, slot = lid >> 3;
    const int t = xcd * per + ((xcd < rem) ? xcd : rem) + slot;
    const int tm = t / gn, tn = t - tm * gn;
    const int bm = tm * BM, bn = tn * BN;
    const int wr = wave >> 1, wc = wave & 1;

    auto stage = [&](int kt, int buf) {
        u16* l = &lds[buf * BUF];
        #pragma unroll
        for (int s = wave; s < SM; s += 4)
            #pragma unroll
            for (int g = 0; g < KG; g++) {
                const u16* gp = A + (size_t)(bm + s * 16 + m0) * lda + kt + g * 32 + q0 * 8;
                ASYNC16(gp, &l[(s * KG + g) * 512]);
            }
        #pragma unroll
        for (int s = wave; s < SN; s += 4)
            #pragma unroll
            for (int g = 0; g < KG; g++) {
                const u16* gp = Bt + (size_t)(bn + s * 16 + m0) * K + kt + g * 32 + q0 * 8;
                ASYNC16(gp, &l[(SM * KG + s * KG + g) * 512]);
            }
    };

    f32x4 acc[WM][WN];
    #pragma unroll
    for (int i = 0; i < WM; i++)
        #pragma unroll
        for (int j = 0; j < WN; j++)
            acc[i][j] = (f32x4){0.f, 0.f, 0.f, 0.f};

    stage(0, 0);
    const int nIter = K / BK;
    for (int it = 0; it < nIter; ++it) {
        __syncthreads();                         // drains stage(it)
        if (it + 1 < nIter) stage((it + 1) * BK, (it + 1) & 1);
        const u16* l = &lds[(it & 1) * BUF];
        short8 af[WM][KG], bf[WN][KG];
        #pragma unroll
        for (int i = 0; i < WM; i++)
            #pragma unroll
            for (int g = 0; g < KG; g++)
                af[i][g] = *(const short8*)&l[(((wr * WM + i) * KG + g) * 64 + lane) * 8];
        #pragma unroll
        for (int j = 0; j < WN; j++)
            #pragma unroll
            for (int g = 0; g < KG; g++)
                bf[j][g] = *(const short8*)&l[((SM * KG + (wc * WN + j) * KG + g) * 64 + lane) * 8];
        #pragma unroll
        for (int g = 0; g < KG; g++)
            #pragma unroll
            for (int i = 0; i < WM; i++)
                #pragma unroll
                for (int j = 0; j < WN; j++)
                    acc[i][j] = __builtin_amdgcn_mfma_f32_16x16x32_bf16(
                        af[i][g], bf[j][g], acc[i][j], 0, 0, 0);
    }

    #pragma unroll
    for (int i = 0; i < WM; i++) {
        #pragma unroll
        for (int j = 0; j < WN; j++) {
            const int col = bn + (wc * WN + j) * 16 + m0;
            if (col >= Nreal) continue;
            const float bv = bias ? bias[col] : 0.f;
            #pragma unroll
            for (int r = 0; r < 4; r++) {
                const int row = bm + (wr * WM + i) * 16 + q0 * 4 + r;
                float v = acc[i][j][r] + bv;
                if (act) v = fmaxf(v, 0.f);
                if (col < split) Cb[(size_t)row * ldcb + col] = f2b(v);
                else             Cf[(size_t)row * ldcf + col - split] = v;
            }
        }
    }
}

// ---------------- unified prep kernel ----------------
struct PrepSrc { const float* s[11]; };

__global__ void __launch_bounds__(256) prep_kernel(
    PrepSrc ps, u16* __restrict__ wt,
    const float* __restrict__ verb_table, const float* __restrict__ role_table,
    const int* __restrict__ gt_verb, const int* __restrict__ role_idx,
    u16* __restrict__ cat,
    const float* __restrict__ v_org, u16* __restrict__ A1,
    const float* __restrict__ img_feat, u16* __restrict__ A2,
    const float* __restrict__ aq_b, const float* __restrict__ qn_b,
    float* __restrict__ aqqn_b)
{
    __shared__ float sm[64 * 50];
    const int bid = blockIdx.x, tid = threadIdx.x;

    if (bid < 11520) {
        const int tStart[12] = {0,640,1152,2176,3200,3712,4736,5760,6784,7808,9472,11520};
        const int tK[11]  = {600,512,1024,1024,512,1024,1024,1024,1024,1624,1024};
        const int tN[11]  = {1024,1024,1024,1024,1024,1024,1024,1024,1024,1024,2001};
        const int tKp[11] = {640,512,1024,1024,512,1024,1024,1024,1024,1664,1024};
        const int tNp[11] = {1024,1024,1024,1024,1024,1024,1024,1024,1024,1024,2048};
        const long tDst[11] = {(long)O_QC,(long)O_AV,(long)O_AQQN,(long)(O_AQQN+1048576),
                               (long)O_VN,(long)O_QKV,(long)(O_QKV+1048576),
                               (long)(O_QKV+2097152),(long)O_WO,(long)O_UQC,(long)O_CLS};
        int e = 0;
        while (bid >= tStart[e + 1]) e++;
        const int local = bid - tStart[e];
        const int ktiles = tKp[e] >> 5;
        const int bx = local % ktiles, by = local / ktiles;
        const float* W = ps.s[e];
        u16* Wt = wt + tDst[e];
        const int K = tK[e], Nn = tN[e], Kp = tKp[e], Np = tNp[e];
        const int kt = bx * 32, nt = by * 32;
        const int tx = tid & 31, ty = tid >> 5;
        for (int i = ty; i < 32; i += 8) {
            const int k = kt + i, n = nt + tx;
            sm[i * 33 + tx] = (k < K && n < Nn) ? W[(size_t)k * Nn + n] : 0.f;
        }
        __syncthreads();
        for (int i = ty; i < 32; i += 8) {
            const int n = nt + i, k = kt + tx;
            if (n < Np && k < Kp) Wt[(size_t)n * Kp + k] = f2b(sm[tx * 33 + i]);
        }
    } else if (bid < 15360) {
        const int idx = (bid - 11520) * 256 + tid;          // NN*640 exactly
        const int n = idx / 640;
        const int col = idx - n * 640;
        const int b = n / Rr, r = n - b * Rr;
        float v = 0.f;
        if (col < Ee)          v = verb_table[(size_t)gt_verb[b] * Ee + col];
        else if (col < 2 * Ee) v = role_table[(size_t)role_idx[b * Rr + r] * Ee + (col - Ee)];
        cat[(size_t)n * 1664 + 1024 + col] = f2b(v);
    } else if (bid < 17408) {
        const int local = bid - 15360;
        const int b = local >> 3, c0 = (local & 7) << 6;
        {
            const int ci = tid >> 2, k0 = tid & 3;
            const float* p = v_org + ((size_t)b * Cc + c0 + ci) * Ksp;
            for (int k = k0; k < Ksp; k += 4) sm[ci * 50 + k] = p[k];
        }
        __syncthreads();
        {
            const int cc = tid & 63, kb = tid >> 6;
            for (int k = kb; k < Ksp; k += 4)
                A1[((size_t)b * Ksp + k) * Cc + c0 + cc] = f2b(sm[cc * 50 + k]);
        }
    } else if (bid < 23680) {
        const int i = (bid - 17408) * 256 + tid;            // 12544*512/4 exactly
        const float4 v = ((const float4*)img_feat)[i];
        ushort4 o;
        o.x = f2b(v.x); o.y = f2b(v.y); o.z = f2b(v.z); o.w = f2b(v.w);
        ((ushort4*)A2)[i] = o;
    } else {
        const int i = (bid - 23680) * 256 + tid;
        if (i < 2048) aqqn_b[i] = (i < 1024) ? aq_b[i] : qn_b[i - 1024];
    }
}

// ---------------- batch-level fused attention (task-merged) ----------------
__global__ void __launch_bounds__(256) att_kernel(
    const u16* __restrict__ Vh0,   // [2][B*49][1024] bf16
    const u16* __restrict__ Q,     // [NN][1024] bf16 (q_att)
    const float* __restrict__ aoW, const float* __restrict__ aoB,
    const u16* __restrict__ IMG0,  // [2][B*49][512] bf16
    u16* __restrict__ Vemb0)       // [2*NN][512] bf16
{
    const int task = blockIdx.x >> 8;
    const int b = blockIdx.x & 255;
    const u16* Vh   = Vh0   + (size_t)task * 12544 * 1024;
    const u16* IMGb = IMG0  + (size_t)task * 12544 * 512;
    u16* Vemb       = Vemb0 + (size_t)task * NN * 512;
    const int tid = threadIdx.x, wave = tid >> 6, lane = tid & 63;
    __shared__ u16 s_qs[16][1032];
    __shared__ float s_log[64][6];
    __shared__ float s_att[49][6];

    for (int n = 0; n < 16; n++) {
        const u16* qp = Q + ((size_t)b * Rr + n) * Hh;
        for (int h = tid; h < 1032; h += 256) {
            u16 v = 0;
            if (n < Rr && h < Hh) v = f2b(b2f(qp[h]) * aoW[h]);
            s_qs[n][h] = v;
        }
    }
    __syncthreads();

    const int m = lane & 15, q = lane >> 4;
    {
        f32x4 acc = (f32x4){0.f, 0.f, 0.f, 0.f};
        const u16* arow = Vh + ((size_t)b * Ksp + wave * 16 + m) * Hh + q * 8;
        const u16* brow = &s_qs[m][q * 8];
        for (int kt = 0; kt < Hh; kt += 32) {
            const short8 af = *(const short8*)(arow + kt);
            const short8 bf = *(const short8*)(brow + kt);
            acc = __builtin_amdgcn_mfma_f32_16x16x32_bf16(af, bf, acc, 0, 0, 0);
        }
        const float aob = aoB[0];
        #pragma unroll
        for (int r = 0; r < 4; r++) {
            const int k = wave * 16 + q * 4 + r;   // C/D: col=lane&15, row=q*4+r
            if (k < Ksp && m < Rr) s_log[k][m] = acc[r] + aob;
        }
    }
    __syncthreads();

    if (wave == 0) {
        for (int r = 0; r < Rr; r++) {
            const float v = (lane < Ksp) ? s_log[lane][r] : -INFINITY;
            float mx = v;
            #pragma unroll
            for (int off = 32; off; off >>= 1) mx = fmaxf(mx, __shfl_down(mx, off));
            mx = __shfl(mx, 0);
            const float e = (lane < Ksp) ? expf(v - mx) : 0.f;
            float s = e;
            #pragma unroll
            for (int off = 32; off; off >>= 1) s += __shfl_down(s, off);
            s = __shfl(s, 0);
            if (lane < Ksp) s_att[lane][r] = e / s;
        }
    }
    __syncthreads();

    float acc2[Rr][2];
    #pragma unroll
    for (int r = 0; r < Rr; r++) { acc2[r][0] = 0.f; acc2[r][1] = 0.f; }
    const u16* ib = IMGb + (size_t)b * Ksp * Cc + tid * 2;
    #pragma unroll 7
    for (int k = 0; k < Ksp; k++) {
        const ushort2 v = *(const ushort2*)(ib + (size_t)k * Cc);
        const float v0 = b2f(v.x), v1 = b2f(v.y);
        #pragma unroll
        for (int r = 0; r < Rr; r++) {
            const float w = s_att[k][r];
            acc2[r][0] += w * v0; acc2[r][1] += w * v1;
        }
    }
    #pragma unroll
    for (int r = 0; r < Rr; r++) {
        ushort2 o; o.x = f2b(acc2[r][0]); o.y = f2b(acc2[r][1]);
        *(ushort2*)(Vemb + ((size_t)b * Rr + r) * Cc + tid * 2) = o;
    }
}

// ---------------- merged MFB: rows 0..NN-1 -> a0f+a0b; NN.. -> vbf ---------
__global__ void __launch_bounds__(256) mfb2_kernel(
    const float* __restrict__ q, const float* __restrict__ v,
    float* __restrict__ a0f, u16* __restrict__ a0b, float* __restrict__ vbf)
{
    const int n = blockIdx.x;
    const int qrow = (n < NN) ? n : n - NN;
    const int tid = threadIdx.x;
    __shared__ float red[4];
    float sv[4];
    float local = 0.f;
    #pragma unroll
    for (int i = 0; i < 4; i++) {
        const int h = tid + i * 256;
        const float z = q[(size_t)qrow * Hh + h] * v[(size_t)n * Hh + h];
        const float s = (z > 0.f) ? sqrtf(z) : -sqrtf(-z);
        sv[i] = s;
        local += s * s;
    }
    #pragma unroll
    for (int off = 32; off; off >>= 1) local += __shfl_down(local, off);
    if ((tid & 63) == 0) red[tid >> 6] = local;
    __syncthreads();
    const float tot = red[0] + red[1] + red[2] + red[3];
    const float inv = 1.f / fmaxf(sqrtf(tot), 1e-12f);
    #pragma unroll
    for (int i = 0; i < 4; i++) {
        const float o = sv[i] * inv;
        if (n < NN) {
            const size_t off2 = (size_t)n * Hh + tid + i * 256;
            a0f[off2] = o; a0b[off2] = f2b(o);
        } else {
            vbf[(size_t)(n - NN) * Hh + tid + i * 256] = o;
        }
    }
}

// ---------------- MFB(out2) + gate + tanh mix fused -> bf16 out_f ---------
__global__ void __launch_bounds__(256) mfb_gate_kernel(
    const float* __restrict__ q, const float* __restrict__ v,
    const float* __restrict__ ovb, const float* __restrict__ oa0,
    u16* __restrict__ outb)
{
    const int n = blockIdx.x;
    const int tid = threadIdx.x;
    __shared__ float red[4];
    float sv[4];
    float local = 0.f;
    #pragma unroll
    for (int i = 0; i < 4; i++) {
        const int h = tid + i * 256;
        const float z = q[(size_t)n * Hh + h] * v[(size_t)n * Hh + h];
        const float s = (z > 0.f) ? sqrtf(z) : -sqrtf(-z);
        sv[i] = s;
        local += s * s;
    }
    #pragma unroll
    for (int off = 32; off; off >>= 1) local += __shfl_down(local, off);
    if ((tid & 63) == 0) red[tid >> 6] = local;
    __syncthreads();
    const float tot = red[0] + red[1] + red[2] + red[3];
    const float inv = 1.f / fmaxf(sqrtf(tot), 1e-12f);
    #pragma unroll
    for (int i = 0; i < 4; i++) {
        const size_t off2 = (size_t)n * Hh + tid + i * 256;
        const float o2 = sv[i] * inv;
        const float ov = ovb[off2], a0 = oa0[off2];
        const float g = 1.f / (1.f + expf(-(o2 + ov)));
        outb[off2] = f2b((1.f - g) * ov + g * tanhf(o2 + a0));
    }
}

// ---------------- neighbor attention (reads fused bf16 qkv [NN][3072]) ----
__global__ void __launch_bounds__(256) nattn_kernel(
    const u16* __restrict__ qkv, const int* __restrict__ mask,
    u16* __restrict__ nv)
{
    const int b = blockIdx.x;
    const int tid = threadIdx.x;
    __shared__ float s_sc[Rr][Rr];
    __shared__ float s_at[Rr][Rr];
    const int wave = tid >> 6, lane = tid & 63;
    for (int p = wave; p < Rr * Rr; p += 4) {
        const int i = p / Rr, j = p - (p / Rr) * Rr;
        const u16* qp = qkv + ((size_t)(b * Rr + i)) * 3072;
        const u16* kp = qkv + ((size_t)(b * Rr + j)) * 3072 + 1024;
        float s = 0.f;
        for (int h = lane * 2; h < Hh; h += 128) {
            const ushort2 qv = *(const ushort2*)(qp + h);
            const ushort2 kv = *(const ushort2*)(kp + h);
            s += b2f(qv.x) * b2f(kv.x) + b2f(qv.y) * b2f(kv.y);
        }
        #pragma unroll
        for (int off = 32; off; off >>= 1) s += __shfl_down(s, off);
        if (lane == 0) s_sc[i][j] = s * 0.03125f;   // 1/sqrt(1024)
    }
    __syncthreads();
    if (tid < Rr) {
        const int i = tid;
        float vals[Rr];
        float m = -INFINITY;
        #pragma unroll
        for (int j = 0; j < Rr; j++) {
            const float mij = (i == j) ? 0.f : (float)mask[b * Rr * Rr + i * Rr + j];
            const float v = (mij > 0.f) ? s_sc[i][j] : -1e9f;
            vals[j] = v;
            m = fmaxf(m, v);
        }
        float ssum = 0.f;
        #pragma unroll
        for (int j = 0; j < Rr; j++) { const float e = expf(vals[j] - m); s_at[i][j] = e; ssum += e; }
        const float invs = 1.f / ssum;
        #pragma unroll
        for (int j = 0; j < Rr; j++) s_at[i][j] *= invs;
    }
    __syncthreads();
    for (int h = tid; h < Hh; h += 256) {
        #pragma unroll
        for (int i = 0; i < Rr; i++) {
            float acc = 0.f;
            #pragma unroll
            for (int j = 0; j < Rr; j++)
                acc += s_at[i][j] * b2f(qkv[((size_t)(b * Rr + j)) * 3072 + 2048 + h]);
            nv[((size_t)(b * Rr + i)) * Hh + h] = f2b(acc);
        }
    }
}

extern "C" void kernel_launch(void* const* d_in, const int* in_sizes, int n_in,
                              void* d_out, int out_size, void* d_ws, size_t ws_size,
                              hipStream_t stream)
{
    const float* v_org      = (const float*)d_in[0];
    const float* img_feat   = (const float*)d_in[1];
    const int*   gt_verb    = (const int*)d_in[2];
    const int*   role_idx   = (const int*)d_in[3];
    const int*   mask       = (const int*)d_in[4];
    const float* verb_table = (const float*)d_in[5];
    const float* role_table = (const float*)d_in[6];
    const float* qc_W  = (const float*)d_in[7];
    const float* qc_b  = (const float*)d_in[8];
    const float* av_W  = (const float*)d_in[9];
    const float* av_b  = (const float*)d_in[10];
    const float* aq_W  = (const float*)d_in[11];
    const float* aq_b  = (const float*)d_in[12];
    const float* ao_W  = (const float*)d_in[13];
    const float* ao_b  = (const float*)d_in[14];
    const float* vn_W  = (const float*)d_in[15];
    const float* vn_b  = (const float*)d_in[16];
    const float* qn_W  = (const float*)d_in[17];
    const float* qn_b  = (const float*)d_in[18];
    const float* Wq    = (const float*)d_in[19];
    const float* Wk    = (const float*)d_in[20];
    const float* Wv    = (const float*)d_in[21];
    const float* Wo    = (const float*)d_in[22];
    const float* uqc_W = (const float*)d_in[23];
    const float* uqc_b = (const float*)d_in[24];
    const float* cls_W = (const float*)d_in[25];
    const float* cls_b = (const float*)d_in[26];
    float* out = (float*)d_out;

    // ---- workspace layout ----
    char* base = (char*)d_ws;
    size_t off = 0;
    auto alloc = [&](size_t bytes) -> char* {
        char* p = base + off;
        off += (bytes + 255) & ~(size_t)255;
        return p;
    };
    u16* wt = (u16*)alloc(WT_ELEMS * 2);                       // ~23.6 MB
    u16* A1 = (u16*)alloc((size_t)12544 * 512 * 2 * 2);        // A1|A2 contiguous
    u16* A2 = A1 + (size_t)12544 * 512;
    u16* v_img = (u16*)alloc((size_t)12544 * 1024 * 2 * 2);    // v_img|v_imgv contig
    u16* v_imgv = v_img + (size_t)12544 * 1024;
    // v_imgv region reused after att: qkv bf16 (9.4MB) + nv bf16 (3.1MB)
    u16* qkv = (u16*)v_imgv;
    u16* nv  = (u16*)((char*)v_imgv + (size_t)NN * 3072 * 2);
    u16* cat    = (u16*)alloc((size_t)NN * 1664 * 2);          // [neigh|rv|pad]
    u16* q_emb  = (u16*)alloc((size_t)NN * 1024 * 2);
    u16* q_att  = (u16*)alloc((size_t)NN * 1024 * 2);
    u16* uq     = (u16*)alloc((size_t)NN * 1024 * 2);
    u16* out_f  = (u16*)alloc((size_t)NN * 1024 * 2);
    u16* v_emb2 = (u16*)alloc((size_t)2 * NN * 512 * 2);       // att1|att_v outputs
    float* v_rep2 = (float*)alloc((size_t)2 * NN * 1024 * 4);  // vn merged out
    float* q_rep = (float*)alloc((size_t)NN * 1024 * 4);
    float* a0f   = (float*)alloc((size_t)NN * 1024 * 4);
    u16*   a0b   = (u16*)alloc((size_t)NN * 1024 * 2);
    float* vbf   = (float*)alloc((size_t)NN * 1024 * 4);
    float* aqqn_b = (float*)alloc(2048 * 4);

    const dim3 blk(256);

    // 1. unified prep
    PrepSrc ps;
    ps.s[0] = qc_W;  ps.s[1] = av_W; ps.s[2] = aq_W; ps.s[3] = qn_W;
    ps.s[4] = vn_W;  ps.s[5] = Wq;   ps.s[6] = Wk;   ps.s[7] = Wv;
    ps.s[8] = Wo;    ps.s[9] = uqc_W; ps.s[10] = cls_W;
    prep_kernel<<<dim3(23688), blk, 0, stream>>>(
        ps, wt, verb_table, role_table, gt_verb, role_idx, cat,
        v_org, A1, img_feat, A2, aq_b, qn_b, aqqn_b);

    // 2. q_emb = relu(rv @ qc_W + b)  [1536,1024,640]
    wgemm_bf16<<<dim3(16, 24), blk, 0, stream>>>(
        cat + 1024, 1664, wt + O_QC, qc_b, q_emb, 1024, nullptr, 0,
        640, 1024, 1024, 1);
    // 3. [v_img; v_imgv] = relu([img0; img_feat] @ av_W + b), M=25088 (LDS dbuf)
    gemm_bf16<128,128,32><<<dim3(8, 196), blk, 0, stream>>>(
        A1, 512, wt + O_AV, av_b, v_img, 1024, nullptr, 0,
        512, 1024, 1024, 1);
    // 4. fused: q_att(bf16) | q_rep(fp32) = relu(q_emb @ [aq|qn] + b)
    wgemm_bf16<<<dim3(32, 24), blk, 0, stream>>>(
        q_emb, 1024, wt + O_AQQN, aqqn_b, q_att, 1024, q_rep, 1024,
        1024, 1024, 2048, 1);
    // 5. att1 + att_v merged -> v_emb2
    att_kernel<<<dim3(512), blk, 0, stream>>>(v_img, q_att, ao_W, ao_b, A1, v_emb2);
    // 6. vn merged: v_rep2 = relu(v_emb2 @ vn + b), M=3072 (fp32)
    wgemm_bf16<<<dim3(16, 48), blk, 0, stream>>>(
        v_emb2, 512, wt + O_VN, vn_b, nullptr, 0, v_rep2, 1024,
        512, 0, 1024, 1);
    // 7. mfb merged: ans0 -> a0f/a0b; out_verb -> vbf
    mfb2_kernel<<<dim3(2 * NN), blk, 0, stream>>>(q_rep, v_rep2, a0f, a0b, vbf);
    // 8. qkv = ans0 @ [Wq|Wk|Wv]  (bf16, into v_imgv region)
    wgemm_bf16<<<dim3(48, 24), blk, 0, stream>>>(
        a0b, 1024, wt + O_QKV, nullptr, qkv, 3072, nullptr, 0,
        1024, 3072, 3072, 0);
    // 9. neighbor attention -> nv (bf16)
    nattn_kernel<<<dim3(Bb), blk, 0, stream>>>(qkv, mask, nv);
    // 10. neigh = nv @ Wo -> cat cols 0..1023 (ldc=1664)
    wgemm_bf16<<<dim3(16, 24), blk, 0, stream>>>(
        nv, 1024, wt + O_WO, nullptr, cat, 1664, nullptr, 0,
        1024, 1024, 1024, 0);
    // 11. uq = relu(cat @ uqc + b), K=1664
    wgemm_bf16<<<dim3(16, 24), blk, 0, stream>>>(
        cat, 1664, wt + O_UQC, uqc_b, uq, 1024, nullptr, 0,
        1664, 1024, 1024, 1);
    // 12. fused: q_att2 | q_rep2 = relu(uq @ [aq|qn] + b)
    wgemm_bf16<<<dim3(32, 24), blk, 0, stream>>>(
        uq, 1024, wt + O_AQQN, aqqn_b, q_att, 1024, q_rep, 1024,
        1024, 1024, 2048, 1);
    // 13. att2 (task 0 only) -> v_emb2 rows 0..NN-1
    att_kernel<<<dim3(Bb), blk, 0, stream>>>(v_img, q_att, ao_W, ao_b, A1, v_emb2);
    // 14. v_rep2[0..NN) = relu(v_emb2 @ vn + b)
    wgemm_bf16<<<dim3(16, 24), blk, 0, stream>>>(
        v_emb2, 512, wt + O_VN, vn_b, nullptr, 0, v_rep2, 1024,
        512, 0, 1024, 1);
    // 15. out2 = MFB(q_rep2, v_rep2); gate with out_verb/ans0 -> out_f
    mfb_gate_kernel<<<dim3(NN), blk, 0, stream>>>(q_rep, v_rep2, vbf, a0f, out_f);
    // 16. logits = out_f @ cls_W + b -> d_out fp32 [1536][2001]
    wgemm_bf16<<<dim3(32, 24), blk, 0, stream>>>(
        out_f, 1024, wt + O_CLS, cls_b, nullptr, 0, out, 2001,
        1024, 0, 2001, 0);
}

// Round 8
// 608.631 us; speedup vs baseline: 1.3002x; 1.3002x over previous
//
#include <hip/hip_runtime.h>
#include <math.h>

typedef unsigned short u16;
typedef __attribute__((ext_vector_type(8))) short short8;
typedef __attribute__((ext_vector_type(4))) float f32x4;

#define Bb 256
#define Rr 6
#define Ksp 49
#define Cc 512
#define Hh 1024
#define Ee 300
#define NN (Bb*Rr)        // 1536
#define NLl 2001

__device__ __forceinline__ u16 f2b(float x) {
    union { float f; unsigned u; } c; c.f = x;
    unsigned r = c.u + 0x7fffu + ((c.u >> 16) & 1u);   // RNE, finite inputs
    return (u16)(r >> 16);
}
__device__ __forceinline__ float b2f(u16 b) {
    union { unsigned u; float f; } c; c.u = ((unsigned)b) << 16; return c.f;
}

// async global->LDS, 16B per lane; LDS dest = wave-uniform base + lane*16
#define ASYNC16(gp, lp) __builtin_amdgcn_global_load_lds( \
    (const __attribute__((address_space(1))) unsigned int*)(gp), \
    (__attribute__((address_space(3))) unsigned int*)(lp), 16, 0, 0)

// ---- weight-pool element offsets (bf16 B^T buffers, contiguous) ----
constexpr size_t O_QC   = 0;                            // [1024][640]
constexpr size_t O_AV   = O_QC   + (size_t)1024*640;    // [1024][512]
constexpr size_t O_AQQN = O_AV   + (size_t)1024*512;    // [2048][1024]
constexpr size_t O_VN   = O_AQQN + (size_t)2048*1024;   // [1024][512]
constexpr size_t O_QKV  = O_VN   + (size_t)1024*512;    // [3072][1024]
constexpr size_t O_WO   = O_QKV  + (size_t)3072*1024;   // [1024][1024]
constexpr size_t O_UQC  = O_WO   + (size_t)1024*1024;   // [1024][1664]
constexpr size_t O_CLS  = O_UQC  + (size_t)1024*1664;   // [2048][1024]
constexpr size_t WT_ELEMS = O_CLS + (size_t)2048*1024;

// ---------------- bf16 MFMA GEMM, tile <BM,BN,BK>, LDS dbuf ---------------
// TAG is an instrumentation-only template arg: each call site gets a unique
// kernel NAME so rocprof's per-dispatch table identifies stages (R7 lesson:
// budget was under-determined with one shared name).
// Distance-1 double-buffered K-loop, one barrier per iteration (R6 structure:
// big GEMM 99.6 -> 78.6 us). A bf16 [..][lda] row-major, Bt bf16 [N][K],
// K % BK == 0. col<split -> Cb bf16 (ldcb); col>=split -> Cf fp32 (ldcf).
// XCD-contiguous n-fastest tile remap (xcd = hw_lid % 8 heuristic).
template<int TAG, int BM, int BN, int BK>
__global__ void __launch_bounds__(256) gemm_bf16(
    const u16* __restrict__ A, int lda, const u16* __restrict__ Bt,
    const float* __restrict__ bias,
    u16* __restrict__ Cb, int ldcb, float* __restrict__ Cf, int ldcf,
    int K, int split, int Nreal, int act)
{
    constexpr int SM = BM / 16, SN = BN / 16;    // 16-row sub-tiles
    constexpr int KG = BK / 32;                  // k-granules per iteration
    constexpr int WM = BM / 32, WN = BN / 32;    // per-wave 16x16 tiles
    constexpr int BUF = (SM + SN) * KG * 512;    // u16 per buffer
    __shared__ u16 lds[2 * BUF];
    const int tid  = threadIdx.x;
    const int wave = tid >> 6, lane = tid & 63;
    const int m0 = lane & 15, q0 = lane >> 4;

    const int gn = gridDim.x;
    const int nblk = gn * gridDim.y;
    const int lid = blockIdx.y * gn + blockIdx.x;
    const int per = nblk >> 3, rem = nblk & 7;
    const int xcd = lid & 7, slot = lid >> 3;
    const int t = xcd * per + ((xcd < rem) ? xcd : rem) + slot;
    const int tm = t / gn, tn = t - tm * gn;
    const int bm = tm * BM, bn = tn * BN;
    const int wr = wave >> 1, wc = wave & 1;

    auto stage = [&](int kt, int buf) {
        u16* l = &lds[buf * BUF];
        #pragma unroll
        for (int s = wave; s < SM; s += 4)
            #pragma unroll
            for (int g = 0; g < KG; g++) {
                const u16* gp = A + (size_t)(bm + s * 16 + m0) * lda + kt + g * 32 + q0 * 8;
                ASYNC16(gp, &l[(s * KG + g) * 512]);
            }
        #pragma unroll
        for (int s = wave; s < SN; s += 4)
            #pragma unroll
            for (int g = 0; g < KG; g++) {
                const u16* gp = Bt + (size_t)(bn + s * 16 + m0) * K + kt + g * 32 + q0 * 8;
                ASYNC16(gp, &l[(SM * KG + s * KG + g) * 512]);
            }
    };

    f32x4 acc[WM][WN];
    #pragma unroll
    for (int i = 0; i < WM; i++)
        #pragma unroll
        for (int j = 0; j < WN; j++)
            acc[i][j] = (f32x4){0.f, 0.f, 0.f, 0.f};

    stage(0, 0);
    const int nIter = K / BK;
    for (int it = 0; it < nIter; ++it) {
        __syncthreads();                         // drains stage(it)
        if (it + 1 < nIter) stage((it + 1) * BK, (it + 1) & 1);
        const u16* l = &lds[(it & 1) * BUF];
        short8 af[WM][KG], bf[WN][KG];
        #pragma unroll
        for (int i = 0; i < WM; i++)
            #pragma unroll
            for (int g = 0; g < KG; g++)
                af[i][g] = *(const short8*)&l[(((wr * WM + i) * KG + g) * 64 + lane) * 8];
        #pragma unroll
        for (int j = 0; j < WN; j++)
            #pragma unroll
            for (int g = 0; g < KG; g++)
                bf[j][g] = *(const short8*)&l[((SM * KG + (wc * WN + j) * KG + g) * 64 + lane) * 8];
        #pragma unroll
        for (int g = 0; g < KG; g++)
            #pragma unroll
            for (int i = 0; i < WM; i++)
                #pragma unroll
                for (int j = 0; j < WN; j++)
                    acc[i][j] = __builtin_amdgcn_mfma_f32_16x16x32_bf16(
                        af[i][g], bf[j][g], acc[i][j], 0, 0, 0);
    }

    #pragma unroll
    for (int i = 0; i < WM; i++) {
        #pragma unroll
        for (int j = 0; j < WN; j++) {
            const int col = bn + (wc * WN + j) * 16 + m0;
            if (col >= Nreal) continue;
            const float bv = bias ? bias[col] : 0.f;
            #pragma unroll
            for (int r = 0; r < 4; r++) {
                const int row = bm + (wr * WM + i) * 16 + q0 * 4 + r;
                float v = acc[i][j][r] + bv;
                if (act) v = fmaxf(v, 0.f);
                if (col < split) Cb[(size_t)row * ldcb + col] = f2b(v);
                else             Cf[(size_t)row * ldcf + col - split] = v;
            }
        }
    }
}

// ---------------- unified prep kernel ----------------
struct PrepSrc { const float* s[11]; };

__global__ void __launch_bounds__(256) prep_kernel(
    PrepSrc ps, u16* __restrict__ wt,
    const float* __restrict__ verb_table, const float* __restrict__ role_table,
    const int* __restrict__ gt_verb, const int* __restrict__ role_idx,
    u16* __restrict__ cat,
    const float* __restrict__ v_org, u16* __restrict__ A1,
    const float* __restrict__ img_feat, u16* __restrict__ A2,
    const float* __restrict__ aq_b, const float* __restrict__ qn_b,
    float* __restrict__ aqqn_b)
{
    __shared__ float sm[64 * 50];
    const int bid = blockIdx.x, tid = threadIdx.x;

    if (bid < 11520) {
        const int tStart[12] = {0,640,1152,2176,3200,3712,4736,5760,6784,7808,9472,11520};
        const int tK[11]  = {600,512,1024,1024,512,1024,1024,1024,1024,1624,1024};
        const int tN[11]  = {1024,1024,1024,1024,1024,1024,1024,1024,1024,1024,2001};
        const int tKp[11] = {640,512,1024,1024,512,1024,1024,1024,1024,1664,1024};
        const int tNp[11] = {1024,1024,1024,1024,1024,1024,1024,1024,1024,1024,2048};
        const long tDst[11] = {(long)O_QC,(long)O_AV,(long)O_AQQN,(long)(O_AQQN+1048576),
                               (long)O_VN,(long)O_QKV,(long)(O_QKV+1048576),
                               (long)(O_QKV+2097152),(long)O_WO,(long)O_UQC,(long)O_CLS};
        int e = 0;
        while (bid >= tStart[e + 1]) e++;
        const int local = bid - tStart[e];
        const int ktiles = tKp[e] >> 5;
        const int bx = local % ktiles, by = local / ktiles;
        const float* W = ps.s[e];
        u16* Wt = wt + tDst[e];
        const int K = tK[e], Nn = tN[e], Kp = tKp[e], Np = tNp[e];
        const int kt = bx * 32, nt = by * 32;
        const int tx = tid & 31, ty = tid >> 5;
        for (int i = ty; i < 32; i += 8) {
            const int k = kt + i, n = nt + tx;
            sm[i * 33 + tx] = (k < K && n < Nn) ? W[(size_t)k * Nn + n] : 0.f;
        }
        __syncthreads();
        for (int i = ty; i < 32; i += 8) {
            const int n = nt + i, k = kt + tx;
            if (n < Np && k < Kp) Wt[(size_t)n * Kp + k] = f2b(sm[tx * 33 + i]);
        }
    } else if (bid < 15360) {
        const int idx = (bid - 11520) * 256 + tid;          // NN*640 exactly
        const int n = idx / 640;
        const int col = idx - n * 640;
        const int b = n / Rr, r = n - b * Rr;
        float v = 0.f;
        if (col < Ee)          v = verb_table[(size_t)gt_verb[b] * Ee + col];
        else if (col < 2 * Ee) v = role_table[(size_t)role_idx[b * Rr + r] * Ee + (col - Ee)];
        cat[(size_t)n * 1664 + 1024 + col] = f2b(v);
    } else if (bid < 17408) {
        const int local = bid - 15360;
        const int b = local >> 3, c0 = (local & 7) << 6;
        {
            const int ci = tid >> 2, k0 = tid & 3;
            const float* p = v_org + ((size_t)b * Cc + c0 + ci) * Ksp;
            for (int k = k0; k < Ksp; k += 4) sm[ci * 50 + k] = p[k];
        }
        __syncthreads();
        {
            const int cc = tid & 63, kb = tid >> 6;
            for (int k = kb; k < Ksp; k += 4)
                A1[((size_t)b * Ksp + k) * Cc + c0 + cc] = f2b(sm[cc * 50 + k]);
        }
    } else if (bid < 23680) {
        const int i = (bid - 17408) * 256 + tid;            // 12544*512/4 exactly
        const float4 v = ((const float4*)img_feat)[i];
        ushort4 o;
        o.x = f2b(v.x); o.y = f2b(v.y); o.z = f2b(v.z); o.w = f2b(v.w);
        ((ushort4*)A2)[i] = o;
    } else {
        const int i = (bid - 23680) * 256 + tid;
        if (i < 2048) aqqn_b[i] = (i < 1024) ? aq_b[i] : qn_b[i - 1024];
    }
}

// ---------------- batch-level fused attention (task-merged) ----------------
__global__ void __launch_bounds__(256) att_kernel(
    const u16* __restrict__ Vh0,   // [2][B*49][1024] bf16
    const u16* __restrict__ Q,     // [NN][1024] bf16 (q_att)
    const float* __restrict__ aoW, const float* __restrict__ aoB,
    const u16* __restrict__ IMG0,  // [2][B*49][512] bf16
    u16* __restrict__ Vemb0)       // [2*NN][512] bf16
{
    const int task = blockIdx.x >> 8;
    const int b = blockIdx.x & 255;
    const u16* Vh   = Vh0   + (size_t)task * 12544 * 1024;
    const u16* IMGb = IMG0  + (size_t)task * 12544 * 512;
    u16* Vemb       = Vemb0 + (size_t)task * NN * 512;
    const int tid = threadIdx.x, wave = tid >> 6, lane = tid & 63;
    __shared__ u16 s_qs[16][1032];
    __shared__ float s_log[64][6];
    __shared__ float s_att[49][6];

    for (int n = 0; n < 16; n++) {
        const u16* qp = Q + ((size_t)b * Rr + n) * Hh;
        for (int h = tid; h < 1032; h += 256) {
            u16 v = 0;
            if (n < Rr && h < Hh) v = f2b(b2f(qp[h]) * aoW[h]);
            s_qs[n][h] = v;
        }
    }
    __syncthreads();

    const int m = lane & 15, q = lane >> 4;
    {
        f32x4 acc = (f32x4){0.f, 0.f, 0.f, 0.f};
        const u16* arow = Vh + ((size_t)b * Ksp + wave * 16 + m) * Hh + q * 8;
        const u16* brow = &s_qs[m][q * 8];
        for (int kt = 0; kt < Hh; kt += 32) {
            const short8 af = *(const short8*)(arow + kt);
            const short8 bf = *(const short8*)(brow + kt);
            acc = __builtin_amdgcn_mfma_f32_16x16x32_bf16(af, bf, acc, 0, 0, 0);
        }
        const float aob = aoB[0];
        #pragma unroll
        for (int r = 0; r < 4; r++) {
            const int k = wave * 16 + q * 4 + r;   // C/D: col=lane&15, row=q*4+r
            if (k < Ksp && m < Rr) s_log[k][m] = acc[r] + aob;
        }
    }
    __syncthreads();

    if (wave == 0) {
        for (int r = 0; r < Rr; r++) {
            const float v = (lane < Ksp) ? s_log[lane][r] : -INFINITY;
            float mx = v;
            #pragma unroll
            for (int off = 32; off; off >>= 1) mx = fmaxf(mx, __shfl_down(mx, off));
            mx = __shfl(mx, 0);
            const float e = (lane < Ksp) ? expf(v - mx) : 0.f;
            float s = e;
            #pragma unroll
            for (int off = 32; off; off >>= 1) s += __shfl_down(s, off);
            s = __shfl(s, 0);
            if (lane < Ksp) s_att[lane][r] = e / s;
        }
    }
    __syncthreads();

    float acc2[Rr][2];
    #pragma unroll
    for (int r = 0; r < Rr; r++) { acc2[r][0] = 0.f; acc2[r][1] = 0.f; }
    const u16* ib = IMGb + (size_t)b * Ksp * Cc + tid * 2;
    #pragma unroll 7
    for (int k = 0; k < Ksp; k++) {
        const ushort2 v = *(const ushort2*)(ib + (size_t)k * Cc);
        const float v0 = b2f(v.x), v1 = b2f(v.y);
        #pragma unroll
        for (int r = 0; r < Rr; r++) {
            const float w = s_att[k][r];
            acc2[r][0] += w * v0; acc2[r][1] += w * v1;
        }
    }
    #pragma unroll
    for (int r = 0; r < Rr; r++) {
        ushort2 o; o.x = f2b(acc2[r][0]); o.y = f2b(acc2[r][1]);
        *(ushort2*)(Vemb + ((size_t)b * Rr + r) * Cc + tid * 2) = o;
    }
}

// ---------------- merged MFB: rows 0..NN-1 -> a0f+a0b; NN.. -> vbf ---------
__global__ void __launch_bounds__(256) mfb2_kernel(
    const float* __restrict__ q, const float* __restrict__ v,
    float* __restrict__ a0f, u16* __restrict__ a0b, float* __restrict__ vbf)
{
    const int n = blockIdx.x;
    const int qrow = (n < NN) ? n : n - NN;
    const int tid = threadIdx.x;
    __shared__ float red[4];
    float sv[4];
    float local = 0.f;
    #pragma unroll
    for (int i = 0; i < 4; i++) {
        const int h = tid + i * 256;
        const float z = q[(size_t)qrow * Hh + h] * v[(size_t)n * Hh + h];
        const float s = (z > 0.f) ? sqrtf(z) : -sqrtf(-z);
        sv[i] = s;
        local += s * s;
    }
    #pragma unroll
    for (int off = 32; off; off >>= 1) local += __shfl_down(local, off);
    if ((tid & 63) == 0) red[tid >> 6] = local;
    __syncthreads();
    const float tot = red[0] + red[1] + red[2] + red[3];
    const float inv = 1.f / fmaxf(sqrtf(tot), 1e-12f);
    #pragma unroll
    for (int i = 0; i < 4; i++) {
        const float o = sv[i] * inv;
        if (n < NN) {
            const size_t off2 = (size_t)n * Hh + tid + i * 256;
            a0f[off2] = o; a0b[off2] = f2b(o);
        } else {
            vbf[(size_t)(n - NN) * Hh + tid + i * 256] = o;
        }
    }
}

// ---------------- MFB(out2) + gate + tanh mix fused -> bf16 out_f ---------
__global__ void __launch_bounds__(256) mfb_gate_kernel(
    const float* __restrict__ q, const float* __restrict__ v,
    const float* __restrict__ ovb, const float* __restrict__ oa0,
    u16* __restrict__ outb)
{
    const int n = blockIdx.x;
    const int tid = threadIdx.x;
    __shared__ float red[4];
    float sv[4];
    float local = 0.f;
    #pragma unroll
    for (int i = 0; i < 4; i++) {
        const int h = tid + i * 256;
        const float z = q[(size_t)n * Hh + h] * v[(size_t)n * Hh + h];
        const float s = (z > 0.f) ? sqrtf(z) : -sqrtf(-z);
        sv[i] = s;
        local += s * s;
    }
    #pragma unroll
    for (int off = 32; off; off >>= 1) local += __shfl_down(local, off);
    if ((tid & 63) == 0) red[tid >> 6] = local;
    __syncthreads();
    const float tot = red[0] + red[1] + red[2] + red[3];
    const float inv = 1.f / fmaxf(sqrtf(tot), 1e-12f);
    #pragma unroll
    for (int i = 0; i < 4; i++) {
        const size_t off2 = (size_t)n * Hh + tid + i * 256;
        const float o2 = sv[i] * inv;
        const float ov = ovb[off2], a0 = oa0[off2];
        const float g = 1.f / (1.f + expf(-(o2 + ov)));
        outb[off2] = f2b((1.f - g) * ov + g * tanhf(o2 + a0));
    }
}

// ---------------- neighbor attention (reads fused bf16 qkv [NN][3072]) ----
__global__ void __launch_bounds__(256) nattn_kernel(
    const u16* __restrict__ qkv, const int* __restrict__ mask,
    u16* __restrict__ nv)
{
    const int b = blockIdx.x;
    const int tid = threadIdx.x;
    __shared__ float s_sc[Rr][Rr];
    __shared__ float s_at[Rr][Rr];
    const int wave = tid >> 6, lane = tid & 63;
    for (int p = wave; p < Rr * Rr; p += 4) {
        const int i = p / Rr, j = p - (p / Rr) * Rr;
        const u16* qp = qkv + ((size_t)(b * Rr + i)) * 3072;
        const u16* kp = qkv + ((size_t)(b * Rr + j)) * 3072 + 1024;
        float s = 0.f;
        for (int h = lane * 2; h < Hh; h += 128) {
            const ushort2 qv = *(const ushort2*)(qp + h);
            const ushort2 kv = *(const ushort2*)(kp + h);
            s += b2f(qv.x) * b2f(kv.x) + b2f(qv.y) * b2f(kv.y);
        }
        #pragma unroll
        for (int off = 32; off; off >>= 1) s += __shfl_down(s, off);
        if (lane == 0) s_sc[i][j] = s * 0.03125f;   // 1/sqrt(1024)
    }
    __syncthreads();
    if (tid < Rr) {
        const int i = tid;
        float vals[Rr];
        float m = -INFINITY;
        #pragma unroll
        for (int j = 0; j < Rr; j++) {
            const float mij = (i == j) ? 0.f : (float)mask[b * Rr * Rr + i * Rr + j];
            const float v = (mij > 0.f) ? s_sc[i][j] : -1e9f;
            vals[j] = v;
            m = fmaxf(m, v);
        }
        float ssum = 0.f;
        #pragma unroll
        for (int j = 0; j < Rr; j++) { const float e = expf(vals[j] - m); s_at[i][j] = e; ssum += e; }
        const float invs = 1.f / ssum;
        #pragma unroll
        for (int j = 0; j < Rr; j++) s_at[i][j] *= invs;
    }
    __syncthreads();
    for (int h = tid; h < Hh; h += 256) {
        #pragma unroll
        for (int i = 0; i < Rr; i++) {
            float acc = 0.f;
            #pragma unroll
            for (int j = 0; j < Rr; j++)
                acc += s_at[i][j] * b2f(qkv[((size_t)(b * Rr + j)) * 3072 + 2048 + h]);
            nv[((size_t)(b * Rr + i)) * Hh + h] = f2b(acc);
        }
    }
}

extern "C" void kernel_launch(void* const* d_in, const int* in_sizes, int n_in,
                              void* d_out, int out_size, void* d_ws, size_t ws_size,
                              hipStream_t stream)
{
    const float* v_org      = (const float*)d_in[0];
    const float* img_feat   = (const float*)d_in[1];
    const int*   gt_verb    = (const int*)d_in[2];
    const int*   role_idx   = (const int*)d_in[3];
    const int*   mask       = (const int*)d_in[4];
    const float* verb_table = (const float*)d_in[5];
    const float* role_table = (const float*)d_in[6];
    const float* qc_W  = (const float*)d_in[7];
    const float* qc_b  = (const float*)d_in[8];
    const float* av_W  = (const float*)d_in[9];
    const float* av_b  = (const float*)d_in[10];
    const float* aq_W  = (const float*)d_in[11];
    const float* aq_b  = (const float*)d_in[12];
    const float* ao_W  = (const float*)d_in[13];
    const float* ao_b  = (const float*)d_in[14];
    const float* vn_W  = (const float*)d_in[15];
    const float* vn_b  = (const float*)d_in[16];
    const float* qn_W  = (const float*)d_in[17];
    const float* qn_b  = (const float*)d_in[18];
    const float* Wq    = (const float*)d_in[19];
    const float* Wk    = (const float*)d_in[20];
    const float* Wv    = (const float*)d_in[21];
    const float* Wo    = (const float*)d_in[22];
    const float* uqc_W = (const float*)d_in[23];
    const float* uqc_b = (const float*)d_in[24];
    const float* cls_W = (const float*)d_in[25];
    const float* cls_b = (const float*)d_in[26];
    float* out = (float*)d_out;

    // ---- workspace layout ----
    char* base = (char*)d_ws;
    size_t off = 0;
    auto alloc = [&](size_t bytes) -> char* {
        char* p = base + off;
        off += (bytes + 255) & ~(size_t)255;
        return p;
    };
    u16* wt = (u16*)alloc(WT_ELEMS * 2);                       // ~23.6 MB
    u16* A1 = (u16*)alloc((size_t)12544 * 512 * 2 * 2);        // A1|A2 contiguous
    u16* A2 = A1 + (size_t)12544 * 512;
    u16* v_img = (u16*)alloc((size_t)12544 * 1024 * 2 * 2);    // v_img|v_imgv contig
    u16* v_imgv = v_img + (size_t)12544 * 1024;
    // v_imgv region reused after att: qkv bf16 (9.4MB) + nv bf16 (3.1MB)
    u16* qkv = (u16*)v_imgv;
    u16* nv  = (u16*)((char*)v_imgv + (size_t)NN * 3072 * 2);
    u16* cat    = (u16*)alloc((size_t)NN * 1664 * 2);          // [neigh|rv|pad]
    u16* q_emb  = (u16*)alloc((size_t)NN * 1024 * 2);
    u16* q_att  = (u16*)alloc((size_t)NN * 1024 * 2);
    u16* uq     = (u16*)alloc((size_t)NN * 1024 * 2);
    u16* out_f  = (u16*)alloc((size_t)NN * 1024 * 2);
    u16* v_emb2 = (u16*)alloc((size_t)2 * NN * 512 * 2);       // att1|att_v outputs
    float* v_rep2 = (float*)alloc((size_t)2 * NN * 1024 * 4);  // vn merged out
    float* q_rep = (float*)alloc((size_t)NN * 1024 * 4);
    float* a0f   = (float*)alloc((size_t)NN * 1024 * 4);
    u16*   a0b   = (u16*)alloc((size_t)NN * 1024 * 2);
    float* vbf   = (float*)alloc((size_t)NN * 1024 * 4);
    float* aqqn_b = (float*)alloc(2048 * 4);

    const dim3 blk(256);

    // 1. unified prep
    PrepSrc ps;
    ps.s[0] = qc_W;  ps.s[1] = av_W; ps.s[2] = aq_W; ps.s[3] = qn_W;
    ps.s[4] = vn_W;  ps.s[5] = Wq;   ps.s[6] = Wk;   ps.s[7] = Wv;
    ps.s[8] = Wo;    ps.s[9] = uqc_W; ps.s[10] = cls_W;
    prep_kernel<<<dim3(23688), blk, 0, stream>>>(
        ps, wt, verb_table, role_table, gt_verb, role_idx, cat,
        v_org, A1, img_feat, A2, aq_b, qn_b, aqqn_b);

    // 2. q_emb = relu(rv @ qc_W + b)  [1536,1024,640]
    gemm_bf16<2,32,64,128><<<dim3(16, 48), blk, 0, stream>>>(
        cat + 1024, 1664, wt + O_QC, qc_b, q_emb, 1024, nullptr, 0,
        640, 1024, 1024, 1);
    // 3. [v_img; v_imgv] = relu([img0; img_feat] @ av_W + b), M=25088
    gemm_bf16<3,128,128,32><<<dim3(8, 196), blk, 0, stream>>>(
        A1, 512, wt + O_AV, av_b, v_img, 1024, nullptr, 0,
        512, 1024, 1024, 1);
    // 4. fused: q_att(bf16) | q_rep(fp32) = relu(q_emb @ [aq|qn] + b)
    gemm_bf16<4,32,64,128><<<dim3(32, 48), blk, 0, stream>>>(
        q_emb, 1024, wt + O_AQQN, aqqn_b, q_att, 1024, q_rep, 1024,
        1024, 1024, 2048, 1);
    // 5. att1 + att_v merged -> v_emb2
    att_kernel<<<dim3(512), blk, 0, stream>>>(v_img, q_att, ao_W, ao_b, A1, v_emb2);
    // 6. vn merged: v_rep2 = relu(v_emb2 @ vn + b), M=3072 (fp32)
    gemm_bf16<6,32,64,128><<<dim3(16, 96), blk, 0, stream>>>(
        v_emb2, 512, wt + O_VN, vn_b, nullptr, 0, v_rep2, 1024,
        512, 0, 1024, 1);
    // 7. mfb merged: ans0 -> a0f/a0b; out_verb -> vbf
    mfb2_kernel<<<dim3(2 * NN), blk, 0, stream>>>(q_rep, v_rep2, a0f, a0b, vbf);
    // 8. qkv = ans0 @ [Wq|Wk|Wv]  (bf16, into v_imgv region)
    gemm_bf16<8,32,64,128><<<dim3(48, 48), blk, 0, stream>>>(
        a0b, 1024, wt + O_QKV, nullptr, qkv, 3072, nullptr, 0,
        1024, 3072, 3072, 0);
    // 9. neighbor attention -> nv (bf16)
    nattn_kernel<<<dim3(Bb), blk, 0, stream>>>(qkv, mask, nv);
    // 10. neigh = nv @ Wo -> cat cols 0..1023 (ldc=1664)
    gemm_bf16<10,32,64,128><<<dim3(16, 48), blk, 0, stream>>>(
        nv, 1024, wt + O_WO, nullptr, cat, 1664, nullptr, 0,
        1024, 1024, 1024, 0);
    // 11. uq = relu(cat @ uqc + b), K=1664
    gemm_bf16<11,32,64,128><<<dim3(16, 48), blk, 0, stream>>>(
        cat, 1664, wt + O_UQC, uqc_b, uq, 1024, nullptr, 0,
        1664, 1024, 1024, 1);
    // 12. fused: q_att2 | q_rep2 = relu(uq @ [aq|qn] + b)
    gemm_bf16<12,32,64,128><<<dim3(32, 48), blk, 0, stream>>>(
        uq, 1024, wt + O_AQQN, aqqn_b, q_att, 1024, q_rep, 1024,
        1024, 1024, 2048, 1);
    // 13. att2 (task 0 only) -> v_emb2 rows 0..NN-1
    att_kernel<<<dim3(Bb), blk, 0, stream>>>(v_img, q_att, ao_W, ao_b, A1, v_emb2);
    // 14. v_rep2[0..NN) = relu(v_emb2 @ vn + b)
    gemm_bf16<14,32,64,128><<<dim3(16, 48), blk, 0, stream>>>(
        v_emb2, 512, wt + O_VN, vn_b, nullptr, 0, v_rep2, 1024,
        512, 0, 1024, 1);
    // 15. out2 = MFB(q_rep2, v_rep2); gate with out_verb/ans0 -> out_f
    mfb_gate_kernel<<<dim3(NN), blk, 0, stream>>>(q_rep, v_rep2, vbf, a0f, out_f);
    // 16. logits = out_f @ cls_W + b -> d_out fp32 [1536][2001]
    gemm_bf16<16,32,64,128><<<dim3(32, 48), blk, 0, stream>>>(
        out_f, 1024, wt + O_CLS, cls_b, nullptr, 0, out, 2001,
        1024, 0, 2001, 0);
}

// Round 9
// 599.906 us; speedup vs baseline: 1.3191x; 1.0145x over previous
//
#include <hip/hip_runtime.h>
#include <math.h>

typedef unsigned short u16;
typedef __attribute__((ext_vector_type(8))) short short8;
typedef __attribute__((ext_vector_type(4))) float f32x4;

#define Bb 256
#define Rr 6
#define Ksp 49
#define Cc 512
#define Hh 1024
#define Ee 300
#define NN (Bb*Rr)        // 1536
#define NLl 2001

__device__ __forceinline__ u16 f2b(float x) {
    union { float f; unsigned u; } c; c.f = x;
    unsigned r = c.u + 0x7fffu + ((c.u >> 16) & 1u);   // RNE, finite inputs
    return (u16)(r >> 16);
}
__device__ __forceinline__ float b2f(u16 b) {
    union { unsigned u; float f; } c; c.u = ((unsigned)b) << 16; return c.f;
}

// async global->LDS, 16B per lane; LDS dest = wave-uniform base + lane*16
#define ASYNC16(gp, lp) __builtin_amdgcn_global_load_lds( \
    (const __attribute__((address_space(1))) unsigned int*)(gp), \
    (__attribute__((address_space(3))) unsigned int*)(lp), 16, 0, 0)

// ---- weight-pool element offsets (bf16 B^T buffers) ----
constexpr size_t O_QC   = 0;                            // [1024][640]
constexpr size_t O_UQCB = O_QC   + (size_t)1024*640;    // [1024][640] (uqc rows 1024..1623 ^T) — contiguous with O_QC for N=2048 merged GEMM
constexpr size_t O_AV   = O_UQCB + (size_t)1024*640;    // [1024][512]
constexpr size_t O_AQQN = O_AV   + (size_t)1024*512;    // [2048][1024]
constexpr size_t O_VN   = O_AQQN + (size_t)2048*1024;   // [1024][512]
constexpr size_t O_QKV  = O_VN   + (size_t)1024*512;    // [3072][1024] = Wq^T | Wk^T | WvWo^T (3rd written by big2)
constexpr size_t O_WO   = O_QKV  + (size_t)3072*1024;   // [1024][1024] Wo^T (A of WvWo task)
constexpr size_t O_UQCT = O_WO   + (size_t)1024*1024;   // [1024][1024] (uqc rows 0..1023 ^T)
constexpr size_t O_CLS  = O_UQCT + (size_t)1024*1024;   // [2048][1024]
constexpr size_t O_WVP  = O_CLS  + (size_t)2048*1024;   // [1024][1024] Wv plain bf16 (Bt of WvWo task)
constexpr size_t WT_ELEMS = O_WVP + (size_t)2048*1024;

// ---------------- small/medium bf16 MFMA GEMM, LDS dbuf -------------------
// TAG = instrumentation-only (unique kernel name per call site).
// A bf16 [..][lda], Bt bf16 [N][K], K % BK == 0. Optional fp32 addend Cadd
// (added before activation). col<split -> Cb bf16; col>=split -> Cf fp32.
// act bit0 = relu on bf16 half, bit1 = relu on fp32 half.
template<int TAG, int BM, int BN, int BK>
__global__ void __launch_bounds__(256) gemm_bf16(
    const u16* __restrict__ A, int lda, const u16* __restrict__ Bt,
    const float* __restrict__ bias, const float* __restrict__ Cadd, int ldadd,
    u16* __restrict__ Cb, int ldcb, float* __restrict__ Cf, int ldcf,
    int K, int split, int Nreal, int act)
{
    constexpr int SM = BM / 16, SN = BN / 16;
    constexpr int KG = BK / 32;
    constexpr int WM = BM / 32, WN = BN / 32;
    constexpr int BUF = (SM + SN) * KG * 512;
    __shared__ u16 lds[2 * BUF];
    const int tid  = threadIdx.x;
    const int wave = tid >> 6, lane = tid & 63;
    const int m0 = lane & 15, q0 = lane >> 4;

    const int gn = gridDim.x;
    const int nblk = gn * gridDim.y;
    const int lid = blockIdx.y * gn + blockIdx.x;
    const int per = nblk >> 3, rem = nblk & 7;
    const int xcd = lid & 7, slot = lid >> 3;
    const int t = xcd * per + ((xcd < rem) ? xcd : rem) + slot;
    const int tm = t / gn, tn = t - tm * gn;
    const int bm = tm * BM, bn = tn * BN;
    const int wr = wave >> 1, wc = wave & 1;

    auto stage = [&](int kt, int buf) {
        u16* l = &lds[buf * BUF];
        #pragma unroll
        for (int s = wave; s < SM; s += 4)
            #pragma unroll
            for (int g = 0; g < KG; g++) {
                const u16* gp = A + (size_t)(bm + s * 16 + m0) * lda + kt + g * 32 + q0 * 8;
                ASYNC16(gp, &l[(s * KG + g) * 512]);
            }
        #pragma unroll
        for (int s = wave; s < SN; s += 4)
            #pragma unroll
            for (int g = 0; g < KG; g++) {
                const u16* gp = Bt + (size_t)(bn + s * 16 + m0) * K + kt + g * 32 + q0 * 8;
                ASYNC16(gp, &l[(SM * KG + s * KG + g) * 512]);
            }
    };

    f32x4 acc[WM][WN];
    #pragma unroll
    for (int i = 0; i < WM; i++)
        #pragma unroll
        for (int j = 0; j < WN; j++)
            acc[i][j] = (f32x4){0.f, 0.f, 0.f, 0.f};

    stage(0, 0);
    const int nIter = K / BK;
    for (int it = 0; it < nIter; ++it) {
        __syncthreads();
        if (it + 1 < nIter) stage((it + 1) * BK, (it + 1) & 1);
        const u16* l = &lds[(it & 1) * BUF];
        short8 af[WM][KG], bf[WN][KG];
        #pragma unroll
        for (int i = 0; i < WM; i++)
            #pragma unroll
            for (int g = 0; g < KG; g++)
                af[i][g] = *(const short8*)&l[(((wr * WM + i) * KG + g) * 64 + lane) * 8];
        #pragma unroll
        for (int j = 0; j < WN; j++)
            #pragma unroll
            for (int g = 0; g < KG; g++)
                bf[j][g] = *(const short8*)&l[((SM * KG + (wc * WN + j) * KG + g) * 64 + lane) * 8];
        #pragma unroll
        for (int g = 0; g < KG; g++)
            #pragma unroll
            for (int i = 0; i < WM; i++)
                #pragma unroll
                for (int j = 0; j < WN; j++)
                    acc[i][j] = __builtin_amdgcn_mfma_f32_16x16x32_bf16(
                        af[i][g], bf[j][g], acc[i][j], 0, 0, 0);
    }

    #pragma unroll
    for (int i = 0; i < WM; i++) {
        #pragma unroll
        for (int j = 0; j < WN; j++) {
            const int col = bn + (wc * WN + j) * 16 + m0;
            if (col >= Nreal) continue;
            const float bv = bias ? bias[col] : 0.f;
            #pragma unroll
            for (int r = 0; r < 4; r++) {
                const int row = bm + (wr * WM + i) * 16 + q0 * 4 + r;
                float v = acc[i][j][r] + bv;
                if (Cadd) v += Cadd[(size_t)row * ldadd + col];
                if (col < split) {
                    if (act & 1) v = fmaxf(v, 0.f);
                    Cb[(size_t)row * ldcb + col] = f2b(v);
                } else {
                    if (act & 2) v = fmaxf(v, 0.f);
                    Cf[(size_t)row * ldcf + col - split] = v;
                }
            }
        }
    }
}

// ---------------- big 2-task GEMM, 128x128x32 dbuf + coalesced epilogue ---
// task0: [v_img;v_imgv] = relu([img0;img_feat] @ av_W + b)  (1568 blocks)
// task1: WvWo^T = Wo^T @ Wv  -> wt_qkv third block            (64 blocks)
// Epilogue round-trips C through LDS (stride 136, 16B-aligned rows) and
// writes 16B/lane global_store_dwordx4 (R8: 2B scattered stores on 50MB).
struct BT { const u16* A; int lda; const u16* Bt; const float* bias;
            u16* C; int ldc; int K; int act; int gnx; };

__global__ void __launch_bounds__(256) gemm_big2(BT t0, BT t1, int blocks0)
{
    __shared__ u16 lds[17408];                    // max(2*8192 staging, 128*136 ct)
    const int tid  = threadIdx.x;
    const int wave = tid >> 6, lane = tid & 63;
    const int m0 = lane & 15, q0 = lane >> 4;

    const int nblk = gridDim.x;
    const int lid = blockIdx.x;
    const int per = nblk >> 3, rem = nblk & 7;
    const int xcd = lid & 7, slot = lid >> 3;
    const int t = xcd * per + ((xcd < rem) ? xcd : rem) + slot;
    const BT T = (t < blocks0) ? t0 : t1;
    const int tt = (t < blocks0) ? t : t - blocks0;
    const int tm = tt / T.gnx, tn = tt - tm * T.gnx;
    const int bm = tm * 128, bn = tn * 128;
    const int wr = wave >> 1, wc = wave & 1;

    auto stage = [&](int kt, int buf) {
        u16* l = &lds[buf * 8192];
        #pragma unroll
        for (int s = wave; s < 8; s += 4) {
            const u16* gp = T.A + (size_t)(bm + s * 16 + m0) * T.lda + kt + q0 * 8;
            ASYNC16(gp, &l[s * 512]);
        }
        #pragma unroll
        for (int s = wave; s < 8; s += 4) {
            const u16* gp = T.Bt + (size_t)(bn + s * 16 + m0) * T.K + kt + q0 * 8;
            ASYNC16(gp, &l[(8 + s) * 512]);
        }
    };

    f32x4 acc[4][4];
    #pragma unroll
    for (int i = 0; i < 4; i++)
        #pragma unroll
        for (int j = 0; j < 4; j++)
            acc[i][j] = (f32x4){0.f, 0.f, 0.f, 0.f};

    stage(0, 0);
    const int nIter = T.K >> 5;
    for (int it = 0; it < nIter; ++it) {
        __syncthreads();
        if (it + 1 < nIter) stage((it + 1) * 32, (it + 1) & 1);
        const u16* l = &lds[(it & 1) * 8192];
        short8 af[4], bf[4];
        #pragma unroll
        for (int i = 0; i < 4; i++)
            af[i] = *(const short8*)&l[((wr * 4 + i) * 64 + lane) * 8];
        #pragma unroll
        for (int j = 0; j < 4; j++)
            bf[j] = *(const short8*)&l[((8 + wc * 4 + j) * 64 + lane) * 8];
        #pragma unroll
        for (int i = 0; i < 4; i++)
            #pragma unroll
            for (int j = 0; j < 4; j++)
                acc[i][j] = __builtin_amdgcn_mfma_f32_16x16x32_bf16(
                    af[i], bf[j], acc[i][j], 0, 0, 0);
    }

    // ---- coalesced epilogue via LDS (stride 136 u16: 16B-aligned rows) ----
    __syncthreads();                              // staging reads done
    #pragma unroll
    for (int i = 0; i < 4; i++) {
        #pragma unroll
        for (int j = 0; j < 4; j++) {
            const int cl = (wc * 4 + j) * 16 + m0;
            const float bv = T.bias ? T.bias[bn + cl] : 0.f;
            #pragma unroll
            for (int r = 0; r < 4; r++) {
                const int rl = (wr * 4 + i) * 16 + q0 * 4 + r;
                float v = acc[i][j][r] + bv;
                if (T.act) v = fmaxf(v, 0.f);
                lds[rl * 136 + cl] = f2b(v);
            }
        }
    }
    __syncthreads();
    #pragma unroll
    for (int pass = 0; pass < 8; pass++) {
        const int rl = pass * 16 + (tid >> 4);
        const int c8 = (tid & 15) * 8;
        const short8 v = *(const short8*)&lds[rl * 136 + c8];
        *(short8*)(T.C + (size_t)(bm + rl) * T.ldc + bn + c8) = v;
    }
}

// ---------------- unified prep kernel ----------------
// [0,10496) weight transposes; [10496,14336) rv gather -> cat cols 1024..1663;
// [14336,16384) v_org->A1; [16384,22656) img_feat->A2; [22656,23680) Wv plain
// cast; [23680,23696) fused biases (aq|qn and qc|zeros).
struct PrepSrc { const float* s[11]; };

__global__ void __launch_bounds__(256) prep_kernel(
    PrepSrc ps, u16* __restrict__ wt,
    const float* __restrict__ verb_table, const float* __restrict__ role_table,
    const int* __restrict__ gt_verb, const int* __restrict__ role_idx,
    u16* __restrict__ cat,
    const float* __restrict__ v_org, u16* __restrict__ A1,
    const float* __restrict__ img_feat, u16* __restrict__ A2,
    const float* __restrict__ Wv,
    const float* __restrict__ aq_b, const float* __restrict__ qn_b,
    const float* __restrict__ qc_b,
    float* __restrict__ aqqn_b, float* __restrict__ qcz_b)
{
    __shared__ float sm[64 * 50];
    const int bid = blockIdx.x, tid = threadIdx.x;

    if (bid < 10496) {
        const int tStart[12] = {0,640,1152,2176,3200,3712,4736,5760,6784,7808,8448,10496};
        const int tK[11]  = {600,512,1024,1024,512,1024,1024,1024,1024,600,1024};
        const int tN[11]  = {1024,1024,1024,1024,1024,1024,1024,1024,1024,1024,2001};
        const int tKp[11] = {640,512,1024,1024,512,1024,1024,1024,1024,640,1024};
        const int tNp[11] = {1024,1024,1024,1024,1024,1024,1024,1024,1024,1024,2048};
        const long tDst[11] = {(long)O_QC,(long)O_AV,(long)O_AQQN,(long)(O_AQQN+1048576),
                               (long)O_VN,(long)O_QKV,(long)(O_QKV+1048576),
                               (long)O_WO,(long)O_UQCT,(long)O_UQCB,(long)O_CLS};
        int e = 0;
        while (bid >= tStart[e + 1]) e++;
        const int local = bid - tStart[e];
        const int ktiles = tKp[e] >> 5;
        const int bx = local % ktiles, by = local / ktiles;
        const float* W = ps.s[e];
        u16* Wt = wt + tDst[e];
        const int K = tK[e], Nn = tN[e], Kp = tKp[e], Np = tNp[e];
        const int kt = bx * 32, nt = by * 32;
        const int tx = tid & 31, ty = tid >> 5;
        for (int i = ty; i < 32; i += 8) {
            const int k = kt + i, n = nt + tx;
            sm[i * 33 + tx] = (k < K && n < Nn) ? W[(size_t)k * Nn + n] : 0.f;
        }
        __syncthreads();
        for (int i = ty; i < 32; i += 8) {
            const int n = nt + i, k = kt + tx;
            if (n < Np && k < Kp) Wt[(size_t)n * Kp + k] = f2b(sm[tx * 33 + i]);
        }
    } else if (bid < 14336) {
        const int idx = (bid - 10496) * 256 + tid;          // NN*640 exactly
        const int n = idx / 640;
        const int col = idx - n * 640;
        const int b = n / Rr, r = n - b * Rr;
        float v = 0.f;
        if (col < Ee)          v = verb_table[(size_t)gt_verb[b] * Ee + col];
        else if (col < 2 * Ee) v = role_table[(size_t)role_idx[b * Rr + r] * Ee + (col - Ee)];
        cat[(size_t)n * 1664 + 1024 + col] = f2b(v);
    } else if (bid < 16384) {
        const int local = bid - 14336;
        const int b = local >> 3, c0 = (local & 7) << 6;
        {
            const int ci = tid >> 2, k0 = tid & 3;
            const float* p = v_org + ((size_t)b * Cc + c0 + ci) * Ksp;
            for (int k = k0; k < Ksp; k += 4) sm[ci * 50 + k] = p[k];
        }
        __syncthreads();
        {
            const int cc = tid & 63, kb = tid >> 6;
            for (int k = kb; k < Ksp; k += 4)
                A1[((size_t)b * Ksp + k) * Cc + c0 + cc] = f2b(sm[cc * 50 + k]);
        }
    } else if (bid < 22656) {
        const int i = (bid - 16384) * 256 + tid;            // 12544*512/4 exactly
        const float4 v = ((const float4*)img_feat)[i];
        ushort4 o;
        o.x = f2b(v.x); o.y = f2b(v.y); o.z = f2b(v.z); o.w = f2b(v.w);
        ((ushort4*)A2)[i] = o;
    } else if (bid < 23680) {
        const int i = (bid - 22656) * 256 + tid;            // 1024*1024/4 exactly
        const float4 v = ((const float4*)Wv)[i];
        ushort4 o;
        o.x = f2b(v.x); o.y = f2b(v.y); o.z = f2b(v.z); o.w = f2b(v.w);
        ((ushort4*)(wt + O_WVP))[i] = o;
    } else {
        const int i = (bid - 23680) * 256 + tid;
        if (i < 2048)      aqqn_b[i] = (i < 1024) ? aq_b[i] : qn_b[i - 1024];
        else if (i < 4096) {
            const int k = i - 2048;
            qcz_b[k] = (k < 1024) ? qc_b[k] : 0.f;
        }
    }
}

// ---------------- batch-level fused attention (task-merged) ----------------
__global__ void __launch_bounds__(256) att_kernel(
    const u16* __restrict__ Vh0, const u16* __restrict__ Q,
    const float* __restrict__ aoW, const float* __restrict__ aoB,
    const u16* __restrict__ IMG0, u16* __restrict__ Vemb0)
{
    const int task = blockIdx.x >> 8;
    const int b = blockIdx.x & 255;
    const u16* Vh   = Vh0   + (size_t)task * 12544 * 1024;
    const u16* IMGb = IMG0  + (size_t)task * 12544 * 512;
    u16* Vemb       = Vemb0 + (size_t)task * NN * 512;
    const int tid = threadIdx.x, wave = tid >> 6, lane = tid & 63;
    __shared__ u16 s_qs[16][1032];
    __shared__ float s_log[64][6];
    __shared__ float s_att[49][6];

    for (int n = 0; n < 16; n++) {
        const u16* qp = Q + ((size_t)b * Rr + n) * Hh;
        for (int h = tid; h < 1032; h += 256) {
            u16 v = 0;
            if (n < Rr && h < Hh) v = f2b(b2f(qp[h]) * aoW[h]);
            s_qs[n][h] = v;
        }
    }
    __syncthreads();

    const int m = lane & 15, q = lane >> 4;
    {
        f32x4 acc = (f32x4){0.f, 0.f, 0.f, 0.f};
        const u16* arow = Vh + ((size_t)b * Ksp + wave * 16 + m) * Hh + q * 8;
        const u16* brow = &s_qs[m][q * 8];
        for (int kt = 0; kt < Hh; kt += 32) {
            const short8 af = *(const short8*)(arow + kt);
            const short8 bf = *(const short8*)(brow + kt);
            acc = __builtin_amdgcn_mfma_f32_16x16x32_bf16(af, bf, acc, 0, 0, 0);
        }
        const float aob = aoB[0];
        #pragma unroll
        for (int r = 0; r < 4; r++) {
            const int k = wave * 16 + q * 4 + r;   // C/D: col=lane&15, row=q*4+r
            if (k < Ksp && m < Rr) s_log[k][m] = acc[r] + aob;
        }
    }
    __syncthreads();

    if (wave == 0) {
        for (int r = 0; r < Rr; r++) {
            const float v = (lane < Ksp) ? s_log[lane][r] : -INFINITY;
            float mx = v;
            #pragma unroll
            for (int off = 32; off; off >>= 1) mx = fmaxf(mx, __shfl_down(mx, off));
            mx = __shfl(mx, 0);
            const float e = (lane < Ksp) ? expf(v - mx) : 0.f;
            float s = e;
            #pragma unroll
            for (int off = 32; off; off >>= 1) s += __shfl_down(s, off);
            s = __shfl(s, 0);
            if (lane < Ksp) s_att[lane][r] = e / s;
        }
    }
    __syncthreads();

    float acc2[Rr][2];
    #pragma unroll
    for (int r = 0; r < Rr; r++) { acc2[r][0] = 0.f; acc2[r][1] = 0.f; }
    const u16* ib = IMGb + (size_t)b * Ksp * Cc + tid * 2;
    #pragma unroll 7
    for (int k = 0; k < Ksp; k++) {
        const ushort2 v = *(const ushort2*)(ib + (size_t)k * Cc);
        const float v0 = b2f(v.x), v1 = b2f(v.y);
        #pragma unroll
        for (int r = 0; r < Rr; r++) {
            const float w = s_att[k][r];
            acc2[r][0] += w * v0; acc2[r][1] += w * v1;
        }
    }
    #pragma unroll
    for (int r = 0; r < Rr; r++) {
        ushort2 o; o.x = f2b(acc2[r][0]); o.y = f2b(acc2[r][1]);
        *(ushort2*)(Vemb + ((size_t)b * Rr + r) * Cc + tid * 2) = o;
    }
}

// ---------------- merged MFB: rows 0..NN-1 -> a0f+a0b; NN.. -> vbf ---------
__global__ void __launch_bounds__(256) mfb2_kernel(
    const float* __restrict__ q, const float* __restrict__ v,
    float* __restrict__ a0f, u16* __restrict__ a0b, float* __restrict__ vbf)
{
    const int n = blockIdx.x;
    const int qrow = (n < NN) ? n : n - NN;
    const int tid = threadIdx.x;
    __shared__ float red[4];
    float sv[4];
    float local = 0.f;
    #pragma unroll
    for (int i = 0; i < 4; i++) {
        const int h = tid + i * 256;
        const float z = q[(size_t)qrow * Hh + h] * v[(size_t)n * Hh + h];
        const float s = (z > 0.f) ? sqrtf(z) : -sqrtf(-z);
        sv[i] = s;
        local += s * s;
    }
    #pragma unroll
    for (int off = 32; off; off >>= 1) local += __shfl_down(local, off);
    if ((tid & 63) == 0) red[tid >> 6] = local;
    __syncthreads();
    const float tot = red[0] + red[1] + red[2] + red[3];
    const float inv = 1.f / fmaxf(sqrtf(tot), 1e-12f);
    #pragma unroll
    for (int i = 0; i < 4; i++) {
        const float o = sv[i] * inv;
        if (n < NN) {
            const size_t off2 = (size_t)n * Hh + tid + i * 256;
            a0f[off2] = o; a0b[off2] = f2b(o);
        } else {
            vbf[(size_t)(n - NN) * Hh + tid + i * 256] = o;
        }
    }
}

// ---------------- MFB(out2) + gate + tanh mix fused -> bf16 out_f ---------
__global__ void __launch_bounds__(256) mfb_gate_kernel(
    const float* __restrict__ q, const float* __restrict__ v,
    const float* __restrict__ ovb, const float* __restrict__ oa0,
    u16* __restrict__ outb)
{
    const int n = blockIdx.x;
    const int tid = threadIdx.x;
    __shared__ float red[4];
    float sv[4];
    float local = 0.f;
    #pragma unroll
    for (int i = 0; i < 4; i++) {
        const int h = tid + i * 256;
        const float z = q[(size_t)n * Hh + h] * v[(size_t)n * Hh + h];
        const float s = (z > 0.f) ? sqrtf(z) : -sqrtf(-z);
        sv[i] = s;
        local += s * s;
    }
    #pragma unroll
    for (int off = 32; off; off >>= 1) local += __shfl_down(local, off);
    if ((tid & 63) == 0) red[tid >> 6] = local;
    __syncthreads();
    const float tot = red[0] + red[1] + red[2] + red[3];
    const float inv = 1.f / fmaxf(sqrtf(tot), 1e-12f);
    #pragma unroll
    for (int i = 0; i < 4; i++) {
        const size_t off2 = (size_t)n * Hh + tid + i * 256;
        const float o2 = sv[i] * inv;
        const float ov = ovb[off2], a0 = oa0[off2];
        const float g = 1.f / (1.f + expf(-(o2 + ov)));
        outb[off2] = f2b((1.f - g) * ov + g * tanhf(o2 + a0));
    }
}

// ---------------- neighbor attention -> neigh (bf16, strided out) ---------
// v-part of qkv is a0 @ (Wv·Wo), so the weighted sum IS neigh directly.
__global__ void __launch_bounds__(256) nattn_kernel(
    const u16* __restrict__ qkv, const int* __restrict__ mask,
    u16* __restrict__ outp, int ldout)
{
    const int b = blockIdx.x;
    const int tid = threadIdx.x;
    __shared__ float s_sc[Rr][Rr];
    __shared__ float s_at[Rr][Rr];
    const int wave = tid >> 6, lane = tid & 63;
    for (int p = wave; p < Rr * Rr; p += 4) {
        const int i = p / Rr, j = p - (p / Rr) * Rr;
        const u16* qp = qkv + ((size_t)(b * Rr + i)) * 3072;
        const u16* kp = qkv + ((size_t)(b * Rr + j)) * 3072 + 1024;
        float s = 0.f;
        for (int h = lane * 2; h < Hh; h += 128) {
            const ushort2 qv = *(const ushort2*)(qp + h);
            const ushort2 kv = *(const ushort2*)(kp + h);
            s += b2f(qv.x) * b2f(kv.x) + b2f(qv.y) * b2f(kv.y);
        }
        #pragma unroll
        for (int off = 32; off; off >>= 1) s += __shfl_down(s, off);
        if (lane == 0) s_sc[i][j] = s * 0.03125f;   // 1/sqrt(1024)
    }
    __syncthreads();
    if (tid < Rr) {
        const int i = tid;
        float vals[Rr];
        float m = -INFINITY;
        #pragma unroll
        for (int j = 0; j < Rr; j++) {
            const float mij = (i == j) ? 0.f : (float)mask[b * Rr * Rr + i * Rr + j];
            const float v = (mij > 0.f) ? s_sc[i][j] : -1e9f;
            vals[j] = v;
            m = fmaxf(m, v);
        }
        float ssum = 0.f;
        #pragma unroll
        for (int j = 0; j < Rr; j++) { const float e = expf(vals[j] - m); s_at[i][j] = e; ssum += e; }
        const float invs = 1.f / ssum;
        #pragma unroll
        for (int j = 0; j < Rr; j++) s_at[i][j] *= invs;
    }
    __syncthreads();
    for (int h = tid; h < Hh; h += 256) {
        #pragma unroll
        for (int i = 0; i < Rr; i++) {
            float acc = 0.f;
            #pragma unroll
            for (int j = 0; j < Rr; j++)
                acc += s_at[i][j] * b2f(qkv[((size_t)(b * Rr + j)) * 3072 + 2048 + h]);
            outp[((size_t)(b * Rr + i)) * ldout + h] = f2b(acc);
        }
    }
}

extern "C" void kernel_launch(void* const* d_in, const int* in_sizes, int n_in,
                              void* d_out, int out_size, void* d_ws, size_t ws_size,
                              hipStream_t stream)
{
    const float* v_org      = (const float*)d_in[0];
    const float* img_feat   = (const float*)d_in[1];
    const int*   gt_verb    = (const int*)d_in[2];
    const int*   role_idx   = (const int*)d_in[3];
    const int*   mask       = (const int*)d_in[4];
    const float* verb_table = (const float*)d_in[5];
    const float* role_table = (const float*)d_in[6];
    const float* qc_W  = (const float*)d_in[7];
    const float* qc_b  = (const float*)d_in[8];
    const float* av_W  = (const float*)d_in[9];
    const float* av_b  = (const float*)d_in[10];
    const float* aq_W  = (const float*)d_in[11];
    const float* aq_b  = (const float*)d_in[12];
    const float* ao_W  = (const float*)d_in[13];
    const float* ao_b  = (const float*)d_in[14];
    const float* vn_W  = (const float*)d_in[15];
    const float* vn_b  = (const float*)d_in[16];
    const float* qn_W  = (const float*)d_in[17];
    const float* qn_b  = (const float*)d_in[18];
    const float* Wq    = (const float*)d_in[19];
    const float* Wk    = (const float*)d_in[20];
    const float* Wv    = (const float*)d_in[21];
    const float* Wo    = (const float*)d_in[22];
    const float* uqc_W = (const float*)d_in[23];
    const float* uqc_b = (const float*)d_in[24];
    const float* cls_W = (const float*)d_in[25];
    const float* cls_b = (const float*)d_in[26];
    float* out = (float*)d_out;

    // ---- workspace layout ----
    char* base = (char*)d_ws;
    size_t off = 0;
    auto alloc = [&](size_t bytes) -> char* {
        char* p = base + off;
        off += (bytes + 255) & ~(size_t)255;
        return p;
    };
    u16* wt = (u16*)alloc(WT_ELEMS * 2);
    u16* A1 = (u16*)alloc((size_t)12544 * 512 * 2 * 2);        // A1|A2 contiguous
    u16* A2 = A1 + (size_t)12544 * 512;
    u16* v_img = (u16*)alloc((size_t)12544 * 1024 * 2 * 2);    // v_img|v_imgv contig
    u16* v_imgv = v_img + (size_t)12544 * 1024;
    u16* qkv = (u16*)v_imgv;                                   // reused after att
    u16* cat    = (u16*)alloc((size_t)NN * 1664 * 2);          // [neigh|rv|pad]
    u16* q_emb  = (u16*)alloc((size_t)NN * 1024 * 2);
    u16* q_att  = (u16*)alloc((size_t)NN * 1024 * 2);
    u16* uq     = (u16*)alloc((size_t)NN * 1024 * 2);
    u16* out_f  = (u16*)alloc((size_t)NN * 1024 * 2);
    u16* v_emb2 = (u16*)alloc((size_t)2 * NN * 512 * 2);
    float* v_rep2 = (float*)alloc((size_t)2 * NN * 1024 * 4);
    float* q_rep = (float*)alloc((size_t)NN * 1024 * 4);
    float* a0f   = (float*)alloc((size_t)NN * 1024 * 4);
    u16*   a0b   = (u16*)alloc((size_t)NN * 1024 * 2);
    float* vbf   = (float*)alloc((size_t)NN * 1024 * 4);
    float* pre_uq = (float*)alloc((size_t)NN * 1024 * 4);      // rv @ uqc_bot
    float* aqqn_b = (float*)alloc(2048 * 4);
    float* qcz_b  = (float*)alloc(2048 * 4);

    const dim3 blk(256);

    // 1. unified prep
    PrepSrc ps;
    ps.s[0] = qc_W; ps.s[1] = av_W; ps.s[2] = aq_W; ps.s[3] = qn_W;
    ps.s[4] = vn_W; ps.s[5] = Wq;   ps.s[6] = Wk;   ps.s[7] = Wo;
    ps.s[8] = uqc_W; ps.s[9] = uqc_W + (size_t)1024 * 1024; ps.s[10] = cls_W;
    prep_kernel<<<dim3(23696), blk, 0, stream>>>(
        ps, wt, verb_table, role_table, gt_verb, role_idx, cat,
        v_org, A1, img_feat, A2, Wv, aq_b, qn_b, qc_b, aqqn_b, qcz_b);

    // 2. big2: av-GEMM (M=25088) + WvWo^T rider task
    BT t0 = { A1, 512, wt + O_AV, av_b, v_img, 1024, 512, 1, 8 };
    BT t1 = { wt + O_WO, 1024, wt + O_WVP, nullptr,
              wt + O_QKV + (size_t)2 * 1024 * 1024, 1024, 1024, 0, 8 };
    gemm_big2<<<dim3(1568 + 64), blk, 0, stream>>>(t0, t1, 1568);

    // 3. merged: q_emb(bf16) | pre_uq(fp32) = rv @ [qc_W | uqc_bot], K=640
    gemm_bf16<3,32,64,128><<<dim3(32, 48), blk, 0, stream>>>(
        cat + 1024, 1664, wt + O_QC, qcz_b, nullptr, 0,
        q_emb, 1024, pre_uq, 1024, 640, 1024, 2048, 1);
    // 4. fused: q_att(bf16,relu) | q_rep(fp32,relu) = q_emb @ [aq|qn] + b
    gemm_bf16<4,32,64,128><<<dim3(32, 48), blk, 0, stream>>>(
        q_emb, 1024, wt + O_AQQN, aqqn_b, nullptr, 0,
        q_att, 1024, q_rep, 1024, 1024, 1024, 2048, 3);
    // 5. att1 + att_v merged -> v_emb2
    att_kernel<<<dim3(512), blk, 0, stream>>>(v_img, q_att, ao_W, ao_b, A1, v_emb2);
    // 6. vn merged: v_rep2 = relu(v_emb2 @ vn + b), M=3072 (fp32)
    gemm_bf16<6,32,64,128><<<dim3(16, 96), blk, 0, stream>>>(
        v_emb2, 512, wt + O_VN, vn_b, nullptr, 0,
        nullptr, 0, v_rep2, 1024, 512, 0, 1024, 2);
    // 7. mfb merged: ans0 -> a0f/a0b; out_verb -> vbf
    mfb2_kernel<<<dim3(2 * NN), blk, 0, stream>>>(q_rep, v_rep2, a0f, a0b, vbf);
    // 8. qkv = a0 @ [Wq | Wk | WvWo]  (bf16, into v_imgv region)
    gemm_bf16<8,32,64,128><<<dim3(48, 48), blk, 0, stream>>>(
        a0b, 1024, wt + O_QKV, nullptr, nullptr, 0,
        qkv, 3072, nullptr, 0, 1024, 3072, 3072, 0);
    // 9. neighbor attention -> neigh directly into cat cols 0..1023
    nattn_kernel<<<dim3(Bb), blk, 0, stream>>>(qkv, mask, cat, 1664);
    // 10. uq = relu(neigh @ uqc_top + pre_uq + b), K=1024
    gemm_bf16<10,32,64,128><<<dim3(16, 48), blk, 0, stream>>>(
        cat, 1664, wt + O_UQCT, uqc_b, pre_uq, 1024,
        uq, 1024, nullptr, 0, 1024, 1024, 1024, 1);
    // 11. fused: q_att2 | q_rep2 = relu(uq @ [aq|qn] + b)
    gemm_bf16<11,32,64,128><<<dim3(32, 48), blk, 0, stream>>>(
        uq, 1024, wt + O_AQQN, aqqn_b, nullptr, 0,
        q_att, 1024, q_rep, 1024, 1024, 1024, 2048, 3);
    // 12. att2 (task 0 only) -> v_emb2 rows 0..NN-1
    att_kernel<<<dim3(Bb), blk, 0, stream>>>(v_img, q_att, ao_W, ao_b, A1, v_emb2);
    // 13. v_rep2[0..NN) = relu(v_emb2 @ vn + b)
    gemm_bf16<13,32,64,128><<<dim3(16, 48), blk, 0, stream>>>(
        v_emb2, 512, wt + O_VN, vn_b, nullptr, 0,
        nullptr, 0, v_rep2, 1024, 512, 0, 1024, 2);
    // 14. out2 = MFB(q_rep2, v_rep2); gate with out_verb/ans0 -> out_f
    mfb_gate_kernel<<<dim3(NN), blk, 0, stream>>>(q_rep, v_rep2, vbf, a0f, out_f);
    // 15. logits = out_f @ cls_W + b -> d_out fp32 [1536][2001]
    gemm_bf16<15,32,64,128><<<dim3(32, 48), blk, 0, stream>>>(
        out_f, 1024, wt + O_CLS, cls_b, nullptr, 0,
        nullptr, 0, out, 2001, 1024, 0, 2001, 0);
}